// Round 8
// baseline (454.714 us; speedup 1.0000x reference)
//
#include <hip/hip_runtime.h>

#define S_LEN 2048
#define HDIM  2048
#define NHEADS 16
#define DHEAD 128
#define BATCH 2
#define MROWS (BATCH * S_LEN)   // 4096
#define QKVN  (3 * HDIM)        // 6144

typedef _Float16 f16;
typedef _Float16 f16x8 __attribute__((ext_vector_type(8)));
typedef _Float16 f16x4 __attribute__((ext_vector_type(4)));
typedef float    f32x4 __attribute__((ext_vector_type(4)));
typedef float    f32x16 __attribute__((ext_vector_type(16)));

typedef const __attribute__((address_space(1))) void* gas_ptr;
typedef __attribute__((address_space(3))) void*       las_ptr;

#define MFMA16(a, b, c)  __builtin_amdgcn_mfma_f32_16x16x32_f16(a, b, c, 0, 0, 0)
#define MFMA32(a, b, c)  __builtin_amdgcn_mfma_f32_32x32x16_f16(a, b, c, 0, 0, 0)

__device__ __forceinline__ void gl_lds16(const f16* g, f16* lds_wave_base) {
#if defined(__has_builtin) && __has_builtin(__builtin_amdgcn_global_load_lds)
  __builtin_amdgcn_global_load_lds((gas_ptr)g, (las_ptr)lds_wave_base, 16, 0, 0);
#else
  int lane = threadIdx.x & 63;
  ((f16x8*)lds_wave_base)[lane] = *(const f16x8*)g;
#endif
}

// Blocked tile layout for GEMM operands: tile (rt, kt) of logical [rows][K] f16,
// 128 rows x 32 k, stored as [kc(4)][r(128)][8] (8 KB) at tile index rt*(K/32)+kt.

// ---------------- X f32 [4096][2048] -> blocked f16 ----------------
__global__ __launch_bounds__(256) void cvt_blocked_kernel(const float* __restrict__ X,
                                                          f16* __restrict__ Xb) {
  int kt = blockIdx.x;           // K/32 = 64
  int rt = blockIdx.y;           // 32
  int t = threadIdx.x;
  int m = t >> 1, half = t & 1;
  const float* src = X + (size_t)(rt * 128 + m) * HDIM + kt * 32 + half * 16;
  float4 v0 = ((const float4*)src)[0];
  float4 v1 = ((const float4*)src)[1];
  float4 v2 = ((const float4*)src)[2];
  float4 v3 = ((const float4*)src)[3];
  f16x8 a = {(f16)v0.x, (f16)v0.y, (f16)v0.z, (f16)v0.w,
             (f16)v1.x, (f16)v1.y, (f16)v1.z, (f16)v1.w};
  f16x8 b = {(f16)v2.x, (f16)v2.y, (f16)v2.z, (f16)v2.w,
             (f16)v3.x, (f16)v3.y, (f16)v3.z, (f16)v3.w};
  f16* dst = Xb + ((size_t)rt * 64 + kt) * 4096 + ((half * 2) * 128 + m) * 8;
  *(f16x8*)dst = a;
  *(f16x8*)(dst + 1024) = b;
}

// ---------------- W f32 [K][N] -> blocked f16 over n-tiles ----------------
__global__ __launch_bounds__(256) void transpose_cvt_blocked_kernel(
    const float* __restrict__ W, f16* __restrict__ Wb, int K, int N) {
  __shared__ float tile[64][65];
  int k0 = blockIdx.y * 64, n0 = blockIdx.x * 64;
  int tr = threadIdx.x >> 4;
  int tc = (threadIdx.x & 15) * 4;
  int KT = K >> 5;
#pragma unroll
  for (int rr = 0; rr < 4; ++rr) {
    int r = rr * 16 + tr;
    float4 v = *(const float4*)(W + (size_t)(k0 + r) * N + n0 + tc);
    tile[r][tc + 0] = v.x; tile[r][tc + 1] = v.y;
    tile[r][tc + 2] = v.z; tile[r][tc + 3] = v.w;
  }
  __syncthreads();
#pragma unroll
  for (int rr = 0; rr < 4; ++rr) {
    int r = rr * 16 + tr;
    int n = n0 + r;
    int kBase = k0 + tc;
    f16x4 o;
#pragma unroll
    for (int c = 0; c < 4; ++c) o[c] = (f16)tile[tc + c][r];
    int nt = n >> 7, nn = n & 127;
    int kt = kBase >> 5, kc = (kBase >> 3) & 3, j = kBase & 7;
    *(f16x4*)(Wb + ((size_t)nt * KT + kt) * 4096 + (kc * 128 + nn) * 8 + j) = o;
  }
}

// ---------------- GEMM: C = A * B^T (+bias), blocked operands ----------------
// MODE 1: QKV split -> Qr row-major f16, KB/VB attention-blocked (bias added).
//         xoff shifts the n-tile index so the QKV GEMM can run as 2 dispatches.
// MODE 2: f16 partial to Cpart[z], K split by blockIdx.z (no bias).
template <int MODE>
__global__ __launch_bounds__(256) void gemm_kernel(const f16* __restrict__ Ablk,
                                                   const f16* __restrict__ Bblk,
                                                   const float* __restrict__ bias,
                                                   f16* __restrict__ Cpart,
                                                   f16* __restrict__ Qr,
                                                   f16* __restrict__ KB,
                                                   f16* __restrict__ VB,
                                                   int xoff, int M, int N, int K) {
  __shared__ f16 As[4 * 128 * 8];
  __shared__ f16 Bs[4 * 128 * 8];
  int tid = threadIdx.x;
  int lane = tid & 63, w = tid >> 6;
  int lhi = lane >> 4, llo = lane & 15;
  int bx = xoff + blockIdx.x;
  int m0 = blockIdx.y * 128, n0 = bx * 128;
  int wm = (w & 1) * 64, wn = (w >> 1) * 64;
  int KT = K >> 5;
  const f16* Ab = Ablk + (size_t)blockIdx.y * KT * 4096;
  const f16* Bb = Bblk + (size_t)bx * KT * 4096;

  int ktBeg = 0, ktEnd = KT;
  if (MODE == 2) { int half = KT >> 1; ktBeg = blockIdx.z * half; ktEnd = ktBeg + half; }

  f32x4 acc[4][4];
#pragma unroll
  for (int i = 0; i < 4; ++i)
#pragma unroll
    for (int j = 0; j < 4; ++j) acc[i][j] = (f32x4){0.f, 0.f, 0.f, 0.f};

  for (int kt = ktBeg; kt < ktEnd; ++kt) {
    __syncthreads();
#pragma unroll
    for (int i2 = 0; i2 < 2; ++i2) {
      int Lw = i2 * 256 + w * 64;
      gl_lds16(Ab + (size_t)kt * 4096 + Lw * 8 + (lane * 8), As + Lw * 8);
      gl_lds16(Bb + (size_t)kt * 4096 + Lw * 8 + (lane * 8), Bs + Lw * 8);
    }
    __syncthreads();

    f16x8 af[4], bf[4];
#pragma unroll
    for (int i = 0; i < 4; ++i)
      af[i] = *(const f16x8*)(As + (lhi * 128 + wm + i * 16 + llo) * 8);
#pragma unroll
    for (int j = 0; j < 4; ++j)
      bf[j] = *(const f16x8*)(Bs + (lhi * 128 + wn + j * 16 + llo) * 8);
#pragma unroll
    for (int i = 0; i < 4; ++i)
#pragma unroll
      for (int j = 0; j < 4; ++j) acc[i][j] = MFMA16(af[i], bf[j], acc[i][j]);
  }

#pragma unroll
  for (int j = 0; j < 4; ++j) {
    int col = n0 + wn + j * 16 + llo;
    float bv = (MODE == 1) ? bias[col] : 0.f;
#pragma unroll
    for (int i = 0; i < 4; ++i) {
      int rowb = m0 + wm + i * 16 + lhi * 4;
      if (MODE == 2) {
        size_t zoff = (size_t)blockIdx.z * M * N;
#pragma unroll
        for (int r = 0; r < 4; ++r)
          Cpart[zoff + (size_t)(rowb + r) * N + col] = (f16)acc[i][j][r];
      } else {
        int region = n0 >> 11;  // 0:Q 1:K 2:V
        if (region == 0) {
#pragma unroll
          for (int r = 0; r < 4; ++r)
            Qr[(size_t)(rowb + r) * HDIM + col] = (f16)(acc[i][j][r] + bv);
        } else if (region == 1) {
          int cK = col - HDIM;
          int hd = cK >> 7, d = cK & 127, g = d >> 3, dj = d & 7;
#pragma unroll
          for (int r = 0; r < 4; ++r) {
            int row = rowb + r;
            int b = row >> 11, s = row & 2047;
            int kt2 = s >> 6, key = s & 63;
            size_t addr = ((((size_t)(b * 16 + hd) * 32 + kt2) * 16 + g) * 64 + key) * 8 + dj;
            KB[addr] = (f16)(acc[i][j][r] + bv);
          }
        } else {
          int cV = col - 2 * HDIM;
          int hd = cV >> 7, d = cV & 127;
          int row = rowb;
          int b = row >> 11, s = row & 2047;
          int kt2 = s >> 6, key = s & 63;
          int kg = key >> 3, kj = key & 7;
          f16x4 pv = {(f16)(acc[i][j][0] + bv), (f16)(acc[i][j][1] + bv),
                      (f16)(acc[i][j][2] + bv), (f16)(acc[i][j][3] + bv)};
          size_t addr = ((((size_t)(b * 16 + hd) * 32 + kt2) * 8 + kg) * 128 + d) * 8 + kj;
          *(f16x4*)(VB + addr) = pv;
        }
      }
    }
  }
}

// ---------------- bias + split-K merge -> f32 out ----------------
__global__ __launch_bounds__(256) void merge_out_kernel(const f16* __restrict__ Cpart,
                                                        const float* __restrict__ bias,
                                                        float* __restrict__ out) {
  int t = blockIdx.x * 256 + threadIdx.x;   // MROWS*HDIM/8 threads
  int col8 = (t & 255) * 8;
  int row = t >> 8;
  size_t base = (size_t)row * HDIM + col8;
  const size_t MN = (size_t)MROWS * HDIM;
  f16x8 a = *(const f16x8*)(Cpart + base);
  f16x8 b = *(const f16x8*)(Cpart + MN + base);
  float4 b0 = *(const float4*)(bias + col8);
  float4 b1 = *(const float4*)(bias + col8 + 4);
  float4 o0 = {(float)a[0] + (float)b[0] + b0.x, (float)a[1] + (float)b[1] + b0.y,
               (float)a[2] + (float)b[2] + b0.z, (float)a[3] + (float)b[3] + b0.w};
  float4 o1 = {(float)a[4] + (float)b[4] + b1.x, (float)a[5] + (float)b[5] + b1.y,
               (float)a[6] + (float)b[6] + b1.z, (float)a[7] + (float)b[7] + b1.w};
  *(float4*)(out + base) = o0;
  *(float4*)(out + base + 4) = o1;
}

// ---------------- causal flash attention (LDS-staged, balanced segments) ------
// Round-5 configuration (best measured): single-buffered staging, 40 segments,
// __launch_bounds__(256,2). Block: 4 waves, q-tile 128 (32/wave), key-tiles 64.
// S^T = K Q^T (32x32x16), fixed-max softmax p = exp2(s*C1 - C2), O^T = V^T P^T.
__global__ __launch_bounds__(256, 2) void attn_kernel(const f16* __restrict__ Qr,
                                                      const f16* __restrict__ KB,
                                                      const f16* __restrict__ VB,
                                                      f16* __restrict__ Opart,
                                                      float* __restrict__ Lpart) {
  __shared__ f16 Ks[1024 * 8];     // [g(16)][key(64)][8]
  __shared__ f16 Vs[1024 * 8];     // [kg(8)][d(128)][8]
  __shared__ f16 Ps[4][32 * 72];   // per-wave [q(32)][key(64)] stride 72

  int tid = threadIdx.x, lane = tid & 63, w = tid >> 6;
  int l5 = lane & 31, hl = lane >> 5;
  int bh = blockIdx.y, b = bh >> 4, hd = bh & 15;
  int gx = blockIdx.x;             // 0..39

  // decode gx -> (qt, seg): group g = qt>>2 has 4 q-tiles x (g+1) segments
  int g, rem;
  if (gx < 4)       { g = 0; rem = gx; }
  else if (gx < 12) { g = 1; rem = gx - 4; }
  else if (gx < 24) { g = 2; rem = gx - 12; }
  else              { g = 3; rem = gx - 24; }
  int nseg = g + 1;
  int qt = g * 4 + rem / nseg;
  int seg = rem % nseg;
  int cnt = 2 * qt + 2;            // key-tiles this q-tile needs
  int kt0 = seg * cnt / nseg;
  int kt1 = (seg + 1) * cnt / nseg;

  int qbase = qt * 128 + w * 32;
  int qrow = qbase + l5;

  const f16* qp = Qr + (size_t)(b * S_LEN + qrow) * HDIM + hd * DHEAD + hl * 8;
  f16x8 qf[8];
#pragma unroll
  for (int s8 = 0; s8 < 8; ++s8) qf[s8] = *(const f16x8*)(qp + s8 * 16);

  f32x16 oac[4];
#pragma unroll
  for (int mt = 0; mt < 4; ++mt)
#pragma unroll
    for (int r = 0; r < 16; ++r) oac[mt][r] = 0.f;
  float rs = 0.f;

  const float C1 = 0.12752747419986393f;   // log2(e)/sqrt(128)
  const float C2 = 11.541560327111708f;    // 8 * log2(e)

  const f16* KBb = KB + (size_t)bh * 32 * 8192;
  const f16* VBb = VB + (size_t)bh * 32 * 8192;

  for (int kt = kt0; kt < kt1; ++kt) {
    __syncthreads();
    {
      const f16* Kt = KBb + (size_t)kt * 8192;
      const f16* Vt = VBb + (size_t)kt * 8192;
#pragma unroll
      for (int c = 0; c < 4; ++c) {
        int u0 = w * 256 + c * 64;
        gl_lds16(Kt + (size_t)(u0 + lane) * 8, Ks + u0 * 8);
        gl_lds16(Vt + (size_t)(u0 + lane) * 8, Vs + u0 * 8);
      }
    }
    __syncthreads();

    if (kt * 64 <= qbase + 31) {
      f32x16 sac[2];
#pragma unroll
      for (int mt = 0; mt < 2; ++mt)
#pragma unroll
        for (int r = 0; r < 16; ++r) sac[mt][r] = 0.f;
#pragma unroll
      for (int s8 = 0; s8 < 8; ++s8) {
#pragma unroll
        for (int mt = 0; mt < 2; ++mt) {
          f16x8 kf = *(const f16x8*)(Ks + ((s8 * 2 + hl) * 64 + mt * 32 + l5) * 8);
          sac[mt] = MFMA32(kf, qf[s8], sac[mt]);
        }
      }

      bool diag = (kt * 64 + 63 > qbase);
#pragma unroll
      for (int mt = 0; mt < 2; ++mt) {
#pragma unroll
        for (int g4 = 0; g4 < 4; ++g4) {
          f16x4 pk;
#pragma unroll
          for (int r = 0; r < 4; ++r) {
            int keyl = mt * 32 + g4 * 8 + hl * 4 + r;
            float p = __builtin_amdgcn_exp2f(fmaf(sac[mt][g4 * 4 + r], C1, -C2));
            if (diag && (kt * 64 + keyl > qrow)) p = 0.f;
            rs += p;
            pk[r] = (f16)p;
          }
          *(f16x4*)(&Ps[w][l5 * 72 + mt * 32 + g4 * 8 + hl * 4]) = pk;
        }
      }
      asm volatile("s_waitcnt lgkmcnt(0)" ::: "memory");  // same-wave P write->read

#pragma unroll
      for (int ks = 0; ks < 4; ++ks) {
        f16x8 pf = *(const f16x8*)(&Ps[w][l5 * 72 + ks * 16 + hl * 8]);
#pragma unroll
        for (int mt = 0; mt < 4; ++mt) {
          f16x8 vf = *(const f16x8*)(Vs + ((ks * 2 + hl) * 128 + mt * 32 + l5) * 8);
          oac[mt] = MFMA32(vf, pf, oac[mt]);
        }
      }
    }
  }

  // epilogue: partials per slot = (bh, gx); per-slot [lq(128)][d(128)] f16
  float lsum = rs + __shfl_xor(rs, 32, 64);
  int lq = w * 32 + l5;
  size_t slot = (size_t)bh * 40 + gx;
  size_t ob = slot * (128 * DHEAD) + (size_t)lq * DHEAD;
#pragma unroll
  for (int mt = 0; mt < 4; ++mt) {
#pragma unroll
    for (int g4 = 0; g4 < 4; ++g4) {
      int d = mt * 32 + g4 * 8 + hl * 4;
      f16x4 ov = {(f16)oac[mt][g4 * 4 + 0], (f16)oac[mt][g4 * 4 + 1],
                  (f16)oac[mt][g4 * 4 + 2], (f16)oac[mt][g4 * 4 + 3]};
      *(f16x4*)(Opart + ob + d) = ov;
    }
  }
  if (hl == 0) Lpart[slot * 128 + lq] = lsum;
}

// ---------------- merge attn partials -> CTX blocked f16 ----------------
__global__ __launch_bounds__(256) void merge_kernel(const f16* __restrict__ Opart,
                                                    const float* __restrict__ Lpart,
                                                    f16* __restrict__ CTXb) {
  int t = blockIdx.x * 256 + threadIdx.x;  // 32*2048*16 threads
  int d8 = (t & 15) * 8;
  int q = (t >> 4) & 2047;
  int bh = t >> 15;
  int b = bh >> 4, hd = bh & 15;
  int qt = q >> 7, lq = q & 127;
  int g = qt >> 2;
  int nseg = g + 1;
  int gxbase = 2 * g * (g + 1) + (qt & 3) * nseg;
  size_t slot0 = (size_t)bh * 40 + gxbase;
  float acc[8];
#pragma unroll
  for (int j = 0; j < 8; ++j) acc[j] = 0.f;
  float l = 0.f;
  for (int s = 0; s < nseg; ++s) {
    l += Lpart[(slot0 + s) * 128 + lq];
    f16x8 a = *(const f16x8*)(Opart + (slot0 + s) * (128 * DHEAD) + (size_t)lq * DHEAD + d8);
#pragma unroll
    for (int j = 0; j < 8; ++j) acc[j] += (float)a[j];
  }
  float inv = 1.0f / l;
  f16x8 o;
#pragma unroll
  for (int j = 0; j < 8; ++j) o[j] = (f16)(acc[j] * inv);
  // blocked write: row = b*S+q, col = hd*128+d8  (K = HDIM, KT = 64)
  int row = b * S_LEN + q;
  int col = hd * DHEAD + d8;
  int rt = row >> 7, rr = row & 127;
  int kt = col >> 5, kc = (col >> 3) & 3;
  *(f16x8*)(CTXb + ((size_t)rt * 64 + kt) * 4096 + (kc * 128 + rr) * 8) = o;
}

// ---------------- launch ----------------
extern "C" void kernel_launch(void* const* d_in, const int* in_sizes, int n_in,
                              void* d_out, int out_size, void* d_ws, size_t ws_size,
                              hipStream_t stream) {
  const float* X    = (const float*)d_in[0];
  const float* Wqkv = (const float*)d_in[2];
  const float* bqkv = (const float*)d_in[3];
  const float* Wout = (const float*)d_in[4];
  const float* bout = (const float*)d_in[5];
  float* out = (float*)d_out;

  char* ws = (char*)d_ws;
  f16* Xb    = (f16*)ws;  ws += (size_t)MROWS * HDIM * sizeof(f16);    // 16 MiB (reused as CTXb)
  f16* Wqkvb = (f16*)ws;  ws += (size_t)QKVN * HDIM * sizeof(f16);     // 24 MiB
  f16* Woutb = (f16*)ws;  ws += (size_t)HDIM * HDIM * sizeof(f16);     // 8 MiB
  f16* Qr    = (f16*)ws;  ws += (size_t)MROWS * HDIM * sizeof(f16);    // 16 MiB
  f16* KB    = (f16*)ws;  ws += (size_t)32 * 32 * 8192 * sizeof(f16);  // 16 MiB
  f16* VB    = (f16*)ws;  ws += (size_t)32 * 32 * 8192 * sizeof(f16);  // 16 MiB
  f16* Opart = (f16*)ws;  ws += (size_t)32 * 40 * 128 * DHEAD * sizeof(f16);   // 40 MiB
  float* Lpart = (float*)ws;  ws += (size_t)32 * 40 * 128 * sizeof(float);     // 640 KiB
  f16* CTXb  = Xb;        // Xb dead after QKV GEMM
  f16* Cpart = Opart;     // Opart dead after merge_kernel; 2*M*N*2B = 32 MiB fits

  cvt_blocked_kernel<<<dim3(HDIM / 32, MROWS / 128), 256, 0, stream>>>(X, Xb);
  transpose_cvt_blocked_kernel<<<dim3(QKVN / 64, HDIM / 64), 256, 0, stream>>>(Wqkv, Wqkvb, HDIM, QKVN);
  transpose_cvt_blocked_kernel<<<dim3(HDIM / 64, HDIM / 64), 256, 0, stream>>>(Wout, Woutb, HDIM, HDIM);

  // QKV projection as two dispatches (Q | K+V) so attn tops the profile.
  gemm_kernel<1><<<dim3(16, MROWS / 128), 256, 0, stream>>>(
      Xb, Wqkvb, bqkv, nullptr, Qr, KB, VB, 0, MROWS, QKVN, HDIM);
  gemm_kernel<1><<<dim3(32, MROWS / 128), 256, 0, stream>>>(
      Xb, Wqkvb, bqkv, nullptr, Qr, KB, VB, 16, MROWS, QKVN, HDIM);

  attn_kernel<<<dim3(40, 32), 256, 0, stream>>>(Qr, KB, VB, Opart, Lpart);

  merge_kernel<<<(32 * S_LEN * 16) / 256, 256, 0, stream>>>(Opart, Lpart, CTXb);

  gemm_kernel<2><<<dim3(16, MROWS / 128, 2), 256, 0, stream>>>(
      CTXb, Woutb, nullptr, Cpart, nullptr, nullptr, nullptr, 0, MROWS, HDIM, HDIM);

  merge_out_kernel<<<(MROWS * HDIM / 8) / 256, 256, 0, stream>>>(Cpart, bout, out);
}

// Round 9
// 449.478 us; speedup vs baseline: 1.0116x; 1.0116x over previous
//
#include <hip/hip_runtime.h>

#define S_LEN 2048
#define HDIM  2048
#define NHEADS 16
#define DHEAD 128
#define BATCH 2
#define MROWS (BATCH * S_LEN)   // 4096
#define QKVN  (3 * HDIM)        // 6144

typedef _Float16 f16;
typedef _Float16 f16x8 __attribute__((ext_vector_type(8)));
typedef _Float16 f16x4 __attribute__((ext_vector_type(4)));
typedef float    f32x4 __attribute__((ext_vector_type(4)));
typedef float    f32x16 __attribute__((ext_vector_type(16)));

typedef const __attribute__((address_space(1))) void* gas_ptr;
typedef __attribute__((address_space(3))) void*       las_ptr;

#define MFMA16(a, b, c)  __builtin_amdgcn_mfma_f32_16x16x32_f16(a, b, c, 0, 0, 0)
#define MFMA32(a, b, c)  __builtin_amdgcn_mfma_f32_32x32x16_f16(a, b, c, 0, 0, 0)

__device__ __forceinline__ void gl_lds16(const f16* g, f16* lds_wave_base) {
#if defined(__has_builtin) && __has_builtin(__builtin_amdgcn_global_load_lds)
  __builtin_amdgcn_global_load_lds((gas_ptr)g, (las_ptr)lds_wave_base, 16, 0, 0);
#else
  int lane = threadIdx.x & 63;
  ((f16x8*)lds_wave_base)[lane] = *(const f16x8*)g;
#endif
}

// Blocked tile layout for GEMM operands: tile (rt, kt) of logical [rows][K] f16,
// 128 rows x 32 k, stored as [kc(4)][r(128)][8] (8 KB) at tile index rt*(K/32)+kt.

// ---------------- X f32 [4096][2048] -> blocked f16 ----------------
__global__ __launch_bounds__(256) void cvt_blocked_kernel(const float* __restrict__ X,
                                                          f16* __restrict__ Xb) {
  int kt = blockIdx.x;           // K/32 = 64
  int rt = blockIdx.y;           // 32
  int t = threadIdx.x;
  int m = t >> 1, half = t & 1;
  const float* src = X + (size_t)(rt * 128 + m) * HDIM + kt * 32 + half * 16;
  float4 v0 = ((const float4*)src)[0];
  float4 v1 = ((const float4*)src)[1];
  float4 v2 = ((const float4*)src)[2];
  float4 v3 = ((const float4*)src)[3];
  f16x8 a = {(f16)v0.x, (f16)v0.y, (f16)v0.z, (f16)v0.w,
             (f16)v1.x, (f16)v1.y, (f16)v1.z, (f16)v1.w};
  f16x8 b = {(f16)v2.x, (f16)v2.y, (f16)v2.z, (f16)v2.w,
             (f16)v3.x, (f16)v3.y, (f16)v3.z, (f16)v3.w};
  f16* dst = Xb + ((size_t)rt * 64 + kt) * 4096 + ((half * 2) * 128 + m) * 8;
  *(f16x8*)dst = a;
  *(f16x8*)(dst + 1024) = b;
}

// ---------------- W f32 [K][N] -> blocked f16 (coalesced f16x8 stores) --------
// XOR-swizzled f16 LDS tile [n_local(64)][k_local(64)]; output stores are
// f16x8 with 8 lanes contiguous per 128B segment (vs 64x8B scatter before).
__global__ __launch_bounds__(256) void transpose_cvt_blocked_kernel(
    const float* __restrict__ W, f16* __restrict__ Wb, int K, int N) {
  __shared__ f16 T[64 * 64];   // [nl][k] with 16B-group XOR swizzle
  int k0 = blockIdx.y * 64, n0 = blockIdx.x * 64;
  int t = threadIdx.x;
  int tr = t >> 4;             // 0..15
  int tc = (t & 15) * 4;       // 0..60
  int KT = K >> 5;
#pragma unroll
  for (int rr = 0; rr < 4; ++rr) {
    int r = rr * 16 + tr;      // k_local
    float4 v = *(const float4*)(W + (size_t)(k0 + r) * N + n0 + tc);
    float vv[4] = {v.x, v.y, v.z, v.w};
#pragma unroll
    for (int c = 0; c < 4; ++c) {
      int nl = tc + c;
      int sw = ((((r >> 3) ^ (nl & 7)) << 3) | (r & 7));
      T[nl * 64 + sw] = (f16)vv[c];
    }
  }
  __syncthreads();
#pragma unroll
  for (int it = 0; it < 2; ++it) {
    int u = it * 256 + t;      // 512 chunks of 8 f16
    int nl = u >> 3, kg = u & 7;
    f16x8 val = *(const f16x8*)(T + nl * 64 + (((kg ^ (nl & 7)) << 3)));
    int n = n0 + nl, kk = k0 + kg * 8;
    int kt = kk >> 5, kc = (kk >> 3) & 3;
    *(f16x8*)(Wb + ((size_t)(n >> 7) * KT + kt) * 4096 + ((kc * 128 + (n & 127)) * 8)) = val;
  }
}

// ---------------- GEMM: C = A * B^T (+bias), blocked operands ----------------
// MODE 1: QKV split -> Qr row-major f16, KB/VB attention-blocked (bias added).
// MODE 2: f16 partial to Cpart[z], K split by blockIdx.z (no bias).
// Q/K/Cpart epilogues go through a 16KB XOR-swizzled LDS transpose buffer
// (aliased onto As/Bs) so every global store is a coalesced f16x8.
template <int MODE>
__global__ __launch_bounds__(256) void gemm_kernel(const f16* __restrict__ Ablk,
                                                   const f16* __restrict__ Bblk,
                                                   const float* __restrict__ bias,
                                                   f16* __restrict__ Cpart,
                                                   f16* __restrict__ Qr,
                                                   f16* __restrict__ KB,
                                                   f16* __restrict__ VB,
                                                   int M, int N, int K) {
  __shared__ f16 Sh[8192];     // As = Sh[0..4095], Bs = Sh[4096..], Ts aliases all
  f16* As = Sh;
  f16* Bs = Sh + 4096;
  f16* Ts = Sh;                // [row(64)][col(128)] swizzled, used post-loop
  int tid = threadIdx.x;
  int lane = tid & 63, w = tid >> 6;
  int lhi = lane >> 4, llo = lane & 15;
  int m0 = blockIdx.y * 128, n0 = blockIdx.x * 128;
  int wm = (w & 1) * 64, wn = (w >> 1) * 64;
  int KT = K >> 5;
  const f16* Ab = Ablk + (size_t)blockIdx.y * KT * 4096;
  const f16* Bb = Bblk + (size_t)blockIdx.x * KT * 4096;

  int ktBeg = 0, ktEnd = KT;
  if (MODE == 2) { int half = KT >> 1; ktBeg = blockIdx.z * half; ktEnd = ktBeg + half; }

  f32x4 acc[4][4];
#pragma unroll
  for (int i = 0; i < 4; ++i)
#pragma unroll
    for (int j = 0; j < 4; ++j) acc[i][j] = (f32x4){0.f, 0.f, 0.f, 0.f};

  for (int kt = ktBeg; kt < ktEnd; ++kt) {
    __syncthreads();
#pragma unroll
    for (int i2 = 0; i2 < 2; ++i2) {
      int Lw = i2 * 256 + w * 64;
      gl_lds16(Ab + (size_t)kt * 4096 + Lw * 8 + (lane * 8), As + Lw * 8);
      gl_lds16(Bb + (size_t)kt * 4096 + Lw * 8 + (lane * 8), Bs + Lw * 8);
    }
    __syncthreads();

    f16x8 af[4], bf[4];
#pragma unroll
    for (int i = 0; i < 4; ++i)
      af[i] = *(const f16x8*)(As + (lhi * 128 + wm + i * 16 + llo) * 8);
#pragma unroll
    for (int j = 0; j < 4; ++j)
      bf[j] = *(const f16x8*)(Bs + (lhi * 128 + wn + j * 16 + llo) * 8);
#pragma unroll
    for (int i = 0; i < 4; ++i)
#pragma unroll
      for (int j = 0; j < 4; ++j) acc[i][j] = MFMA16(af[i], bf[j], acc[i][j]);
  }

  if (MODE == 1 && (n0 >> 11) == 2) {
    // V region: direct stores; lanes (lhi 0/1, llo) interleave kj to fill
    // full 16B spans -> already coalesced.
#pragma unroll
    for (int j = 0; j < 4; ++j) {
      int col = n0 + wn + j * 16 + llo;
      float bv = bias[col];
      int cV = col - 2 * HDIM;
      int hd = cV >> 7, d = cV & 127;
#pragma unroll
      for (int i = 0; i < 4; ++i) {
        int row = m0 + wm + i * 16 + lhi * 4;
        int b = row >> 11, s = row & 2047;
        int kt2 = s >> 6, key = s & 63;
        int kg = key >> 3, kj = key & 7;
        f16x4 pv = {(f16)(acc[i][j][0] + bv), (f16)(acc[i][j][1] + bv),
                    (f16)(acc[i][j][2] + bv), (f16)(acc[i][j][3] + bv)};
        size_t addr = ((((size_t)(b * 16 + hd) * 32 + kt2) * 8 + kg) * 128 + d) * 8 + kj;
        *(f16x4*)(VB + addr) = pv;
      }
    }
  } else {
    // Q / K / Cpart via LDS transpose bounce, two 64-row halves.
#pragma unroll
    for (int half = 0; half < 2; ++half) {
      __syncthreads();           // As/Bs (or prior Ts) reads complete
      if ((w & 1) == half) {     // these waves own rows half*64..half*64+63
#pragma unroll
        for (int j = 0; j < 4; ++j) {
          int col = n0 + wn + j * 16 + llo;
          float bv = (MODE == 1) ? bias[col] : 0.f;
          int dl = wn + j * 16 + llo;   // local col 0..127
#pragma unroll
          for (int i = 0; i < 4; ++i) {
#pragma unroll
            for (int r = 0; r < 4; ++r) {
              int keyl = i * 16 + lhi * 4 + r;  // local row 0..63
              Ts[keyl * 128 + ((((dl >> 3) ^ (keyl & 7)) << 3) | (dl & 7))] =
                  (f16)(acc[i][j][r] + bv);
            }
          }
        }
      }
      __syncthreads();
      if (MODE == 2) {
        size_t zoff = (size_t)blockIdx.z * M * N;
#pragma unroll
        for (int c = 0; c < 4; ++c) {
          int u = c * 256 + tid;
          int rowl = u >> 4, gp = u & 15;
          f16x8 v = *(const f16x8*)(Ts + rowl * 128 + ((gp ^ (rowl & 7)) << 3));
          *(f16x8*)(Cpart + zoff + (size_t)(m0 + half * 64 + rowl) * N + n0 + gp * 8) = v;
        }
      } else if ((n0 >> 11) == 0) {   // Q: row-major
#pragma unroll
        for (int c = 0; c < 4; ++c) {
          int u = c * 256 + tid;
          int rowl = u >> 4, gp = u & 15;
          f16x8 v = *(const f16x8*)(Ts + rowl * 128 + ((gp ^ (rowl & 7)) << 3));
          *(f16x8*)(Qr + (size_t)(m0 + half * 64 + rowl) * HDIM + n0 + gp * 8) = v;
        }
      } else {                        // K: blocked tile, fully contiguous stores
        int hd = (n0 - HDIM) >> 7;
        int b = m0 >> 11;
        int kt2 = ((m0 & 2047) >> 6) + half;
        size_t tb = ((size_t)(b * 16 + hd) * 32 + kt2) * 8192;
#pragma unroll
        for (int c = 0; c < 4; ++c) {
          int u = c * 256 + tid;      // u = g*64 + key
          int g = u >> 6, key = u & 63;
          f16x8 v = *(const f16x8*)(Ts + key * 128 + ((g ^ (key & 7)) << 3));
          *(f16x8*)(KB + tb + (size_t)u * 8) = v;
        }
      }
    }
  }
}

// ---------------- bias + split-K merge -> f32 out ----------------
__global__ __launch_bounds__(256) void merge_out_kernel(const f16* __restrict__ Cpart,
                                                        const float* __restrict__ bias,
                                                        float* __restrict__ out) {
  int t = blockIdx.x * 256 + threadIdx.x;   // MROWS*HDIM/8 threads
  int col8 = (t & 255) * 8;
  int row = t >> 8;
  size_t base = (size_t)row * HDIM + col8;
  const size_t MN = (size_t)MROWS * HDIM;
  f16x8 a = *(const f16x8*)(Cpart + base);
  f16x8 b = *(const f16x8*)(Cpart + MN + base);
  float4 b0 = *(const float4*)(bias + col8);
  float4 b1 = *(const float4*)(bias + col8 + 4);
  float4 o0 = {(float)a[0] + (float)b[0] + b0.x, (float)a[1] + (float)b[1] + b0.y,
               (float)a[2] + (float)b[2] + b0.z, (float)a[3] + (float)b[3] + b0.w};
  float4 o1 = {(float)a[4] + (float)b[4] + b1.x, (float)a[5] + (float)b[5] + b1.y,
               (float)a[6] + (float)b[6] + b1.z, (float)a[7] + (float)b[7] + b1.w};
  *(float4*)(out + base) = o0;
  *(float4*)(out + base + 4) = o1;
}

// ---------------- causal flash attention (round-5 form, best measured) --------
// Block: 256 thr = 4 waves; q-tile = 128 rows (32/wave); key-tiles of 64.
// grid.x = 24: gx<8 -> qt=gx single block; gx>=8 -> qt=8+(gx-8)/2, 2 key-splits.
// S^T = K Q^T (32x32x16), fixed-max softmax p = exp2(s*C1 - C2), O^T = V^T P^T.
__global__ __launch_bounds__(256, 3) void attn_kernel(const f16* __restrict__ Qr,
                                                      const f16* __restrict__ KB,
                                                      const f16* __restrict__ VB,
                                                      f16* __restrict__ Opart,
                                                      float* __restrict__ Lpart) {
  __shared__ f16 Ks[1024 * 8];     // [g(16)][key(64)][8]
  __shared__ f16 Vs[1024 * 8];     // [kg(8)][d(128)][8]
  __shared__ f16 Ps[4][32 * 72];   // per-wave [q(32)][key(64)] stride 72

  int tid = threadIdx.x, lane = tid & 63, w = tid >> 6;
  int l5 = lane & 31, hl = lane >> 5;
  int bh = blockIdx.y, b = bh >> 4, hd = bh & 15;
  int gx = blockIdx.x;
  int qt, kt0, kt1, slot;
  if (gx < 8) { qt = gx; slot = 0; kt0 = 0; kt1 = 2 * qt + 2; }
  else {
    qt = 8 + ((gx - 8) >> 1); slot = (gx - 8) & 1;
    kt0 = slot ? (qt + 1) : 0;
    kt1 = slot ? (2 * qt + 2) : (qt + 1);
  }

  int qbase = qt * 128 + w * 32;
  int qrow = qbase + l5;

  const f16* qp = Qr + (size_t)(b * S_LEN + qrow) * HDIM + hd * DHEAD + hl * 8;
  f16x8 qf[8];
#pragma unroll
  for (int s8 = 0; s8 < 8; ++s8) qf[s8] = *(const f16x8*)(qp + s8 * 16);

  f32x16 oac[4];
#pragma unroll
  for (int mt = 0; mt < 4; ++mt)
#pragma unroll
    for (int r = 0; r < 16; ++r) oac[mt][r] = 0.f;
  float rs = 0.f;

  const float C1 = 0.12752747419986393f;   // log2(e)/sqrt(128)
  const float C2 = 11.541560327111708f;    // 8 * log2(e)

  const f16* KBb = KB + (size_t)bh * 32 * 8192;
  const f16* VBb = VB + (size_t)bh * 32 * 8192;

  for (int kt = kt0; kt < kt1; ++kt) {
    __syncthreads();
    {
      const f16* Kt = KBb + (size_t)kt * 8192;
      const f16* Vt = VBb + (size_t)kt * 8192;
#pragma unroll
      for (int c = 0; c < 4; ++c) {
        int u0 = w * 256 + c * 64;
        gl_lds16(Kt + (size_t)(u0 + lane) * 8, Ks + u0 * 8);
        gl_lds16(Vt + (size_t)(u0 + lane) * 8, Vs + u0 * 8);
      }
    }
    __syncthreads();

    if (kt * 64 <= qbase + 31) {
      f32x16 sac[2];
#pragma unroll
      for (int mt = 0; mt < 2; ++mt)
#pragma unroll
        for (int r = 0; r < 16; ++r) sac[mt][r] = 0.f;
#pragma unroll
      for (int s8 = 0; s8 < 8; ++s8) {
#pragma unroll
        for (int mt = 0; mt < 2; ++mt) {
          f16x8 kf = *(const f16x8*)(Ks + ((s8 * 2 + hl) * 64 + mt * 32 + l5) * 8);
          sac[mt] = MFMA32(kf, qf[s8], sac[mt]);
        }
      }

      bool diag = (kt * 64 + 63 > qbase);
#pragma unroll
      for (int mt = 0; mt < 2; ++mt) {
#pragma unroll
        for (int g4 = 0; g4 < 4; ++g4) {
          f16x4 pk;
#pragma unroll
          for (int r = 0; r < 4; ++r) {
            int keyl = mt * 32 + g4 * 8 + hl * 4 + r;
            float p = __builtin_amdgcn_exp2f(fmaf(sac[mt][g4 * 4 + r], C1, -C2));
            if (diag && (kt * 64 + keyl > qrow)) p = 0.f;
            rs += p;
            pk[r] = (f16)p;
          }
          *(f16x4*)(&Ps[w][l5 * 72 + mt * 32 + g4 * 8 + hl * 4]) = pk;
        }
      }
      asm volatile("s_waitcnt lgkmcnt(0)" ::: "memory");  // same-wave P write->read

#pragma unroll
      for (int ks = 0; ks < 4; ++ks) {
        f16x8 pf = *(const f16x8*)(&Ps[w][l5 * 72 + ks * 16 + hl * 8]);
#pragma unroll
        for (int mt = 0; mt < 4; ++mt) {
          f16x8 vf = *(const f16x8*)(Vs + ((ks * 2 + hl) * 128 + mt * 32 + l5) * 8);
          oac[mt] = MFMA32(vf, pf, oac[mt]);
        }
      }
    }
  }

  float lsum = rs + __shfl_xor(rs, 32, 64);
  size_t ob = ((size_t)slot * 32 + bh) * S_LEN * DHEAD + (size_t)qrow * DHEAD;
#pragma unroll
  for (int mt = 0; mt < 4; ++mt) {
#pragma unroll
    for (int g4 = 0; g4 < 4; ++g4) {
      int d = mt * 32 + g4 * 8 + hl * 4;
      f16x4 ov = {(f16)oac[mt][g4 * 4 + 0], (f16)oac[mt][g4 * 4 + 1],
                  (f16)oac[mt][g4 * 4 + 2], (f16)oac[mt][g4 * 4 + 3]};
      *(f16x4*)(Opart + ob + d) = ov;
    }
  }
  if (hl == 0) Lpart[((size_t)slot * 32 + bh) * S_LEN + qrow] = lsum;
}

// ---------------- merge attn partials -> CTX blocked f16 ----------------
__global__ __launch_bounds__(256) void merge_kernel(const f16* __restrict__ Opart,
                                                    const float* __restrict__ Lpart,
                                                    f16* __restrict__ CTXb) {
  int t = blockIdx.x * 256 + threadIdx.x;  // 32*2048*16 threads
  int d8 = (t & 15) * 8;
  int q = (t >> 4) & 2047;
  int bh = t >> 15;
  int b = bh >> 4, hd = bh & 15;
  int ns = ((q >> 7) >= 8) ? 2 : 1;
  size_t o0 = ((size_t)bh * S_LEN + q) * DHEAD + d8;
  const size_t OSLOT = (size_t)32 * S_LEN * DHEAD;
  float l = Lpart[(size_t)bh * S_LEN + q];
  f16x8 a = *(const f16x8*)(Opart + o0);
  float acc[8];
#pragma unroll
  for (int j = 0; j < 8; ++j) acc[j] = (float)a[j];
  if (ns == 2) {
    l += Lpart[OSLOT / DHEAD + (size_t)bh * S_LEN + q];
    f16x8 a2 = *(const f16x8*)(Opart + OSLOT + o0);
#pragma unroll
    for (int j = 0; j < 8; ++j) acc[j] += (float)a2[j];
  }
  float inv = 1.0f / l;
  f16x8 o;
#pragma unroll
  for (int j = 0; j < 8; ++j) o[j] = (f16)(acc[j] * inv);
  // blocked write: row = b*S+q, col = hd*128+d8  (K = HDIM, KT = 64)
  int row = b * S_LEN + q;
  int col = hd * DHEAD + d8;
  int rt = row >> 7, rr = row & 127;
  int kt = col >> 5, kc = (col >> 3) & 3;
  *(f16x8*)(CTXb + ((size_t)rt * 64 + kt) * 4096 + (kc * 128 + rr) * 8) = o;
}

// ---------------- launch ----------------
extern "C" void kernel_launch(void* const* d_in, const int* in_sizes, int n_in,
                              void* d_out, int out_size, void* d_ws, size_t ws_size,
                              hipStream_t stream) {
  const float* X    = (const float*)d_in[0];
  const float* Wqkv = (const float*)d_in[2];
  const float* bqkv = (const float*)d_in[3];
  const float* Wout = (const float*)d_in[4];
  const float* bout = (const float*)d_in[5];
  float* out = (float*)d_out;

  char* ws = (char*)d_ws;
  f16* Xb    = (f16*)ws;  ws += (size_t)MROWS * HDIM * sizeof(f16);    // 16 MiB (reused as CTXb)
  f16* Wqkvb = (f16*)ws;  ws += (size_t)QKVN * HDIM * sizeof(f16);     // 24 MiB
  f16* Woutb = (f16*)ws;  ws += (size_t)HDIM * HDIM * sizeof(f16);     // 8 MiB
  f16* Qr    = (f16*)ws;  ws += (size_t)MROWS * HDIM * sizeof(f16);    // 16 MiB
  f16* KB    = (f16*)ws;  ws += (size_t)32 * 32 * 8192 * sizeof(f16);  // 16 MiB
  f16* VB    = (f16*)ws;  ws += (size_t)32 * 32 * 8192 * sizeof(f16);  // 16 MiB
  f16* Opart = (f16*)ws;  ws += (size_t)2 * 32 * S_LEN * DHEAD * sizeof(f16);  // 32 MiB
  float* Lpart = (float*)ws;  ws += (size_t)2 * 32 * S_LEN * sizeof(float);    // 512 KiB
  f16* CTXb  = Xb;        // Xb dead after QKV GEMM
  f16* Cpart = Opart;     // Opart dead after merge_kernel; 2*M*N*2B = 32 MiB fits

  cvt_blocked_kernel<<<dim3(HDIM / 32, MROWS / 128), 256, 0, stream>>>(X, Xb);
  transpose_cvt_blocked_kernel<<<dim3(QKVN / 64, HDIM / 64), 256, 0, stream>>>(Wqkv, Wqkvb, HDIM, QKVN);
  transpose_cvt_blocked_kernel<<<dim3(HDIM / 64, HDIM / 64), 256, 0, stream>>>(Wout, Woutb, HDIM, HDIM);

  gemm_kernel<1><<<dim3(QKVN / 128, MROWS / 128), 256, 0, stream>>>(
      Xb, Wqkvb, bqkv, nullptr, Qr, KB, VB, MROWS, QKVN, HDIM);

  attn_kernel<<<dim3(24, 32), 256, 0, stream>>>(Qr, KB, VB, Opart, Lpart);

  merge_kernel<<<(32 * S_LEN * 16) / 256, 256, 0, stream>>>(Opart, Lpart, CTXb);

  gemm_kernel<2><<<dim3(HDIM / 128, MROWS / 128, 2), 256, 0, stream>>>(
      CTXb, Woutb, nullptr, Cpart, nullptr, nullptr, nullptr, MROWS, HDIM, HDIM);

  merge_out_kernel<<<(MROWS * HDIM / 8) / 256, 256, 0, stream>>>(Cpart, bout, out);
}

// Round 10
// 408.495 us; speedup vs baseline: 1.1131x; 1.1003x over previous
//
#include <hip/hip_runtime.h>

#define S_LEN 2048
#define HDIM  2048
#define NHEADS 16
#define DHEAD 128
#define BATCH 2
#define MROWS (BATCH * S_LEN)   // 4096
#define QKVN  (3 * HDIM)        // 6144

typedef _Float16 f16;
typedef _Float16 f16x8 __attribute__((ext_vector_type(8)));
typedef _Float16 f16x4 __attribute__((ext_vector_type(4)));
typedef float    f32x4 __attribute__((ext_vector_type(4)));
typedef float    f32x16 __attribute__((ext_vector_type(16)));

typedef const __attribute__((address_space(1))) void* gas_ptr;
typedef __attribute__((address_space(3))) void*       las_ptr;

#define MFMA16(a, b, c)  __builtin_amdgcn_mfma_f32_16x16x32_f16(a, b, c, 0, 0, 0)
#define MFMA32(a, b, c)  __builtin_amdgcn_mfma_f32_32x32x16_f16(a, b, c, 0, 0, 0)

__device__ __forceinline__ void gl_lds16(const f16* g, f16* lds_wave_base) {
#if defined(__has_builtin) && __has_builtin(__builtin_amdgcn_global_load_lds)
  __builtin_amdgcn_global_load_lds((gas_ptr)g, (las_ptr)lds_wave_base, 16, 0, 0);
#else
  int lane = threadIdx.x & 63;
  ((f16x8*)lds_wave_base)[lane] = *(const f16x8*)g;
#endif
}

// Blocked tile layout for GEMM operands: tile (rt, kt) of logical [rows][K] f16,
// 128 rows x 32 k, stored as [kc(4)][r(128)][8] (8 KB) at tile index rt*(K/32)+kt.

// ---------------- fused prep: X cvt + both weight transposes ------------------
// flat grid: [0,2048) cvt X; [2048,5120) transpose Wqkv; [5120,6144) transpose Wout.
__device__ __forceinline__ void transpose_tile(const float* __restrict__ W,
                                               f16* __restrict__ Wb,
                                               int K, int N, int k0, int n0,
                                               float* tile /*[64][65]*/) {
  int tr = threadIdx.x >> 4;
  int tc = (threadIdx.x & 15) * 4;
  int KT = K >> 5;
#pragma unroll
  for (int rr = 0; rr < 4; ++rr) {
    int r = rr * 16 + tr;
    float4 v = *(const float4*)(W + (size_t)(k0 + r) * N + n0 + tc);
    tile[r * 65 + tc + 0] = v.x; tile[r * 65 + tc + 1] = v.y;
    tile[r * 65 + tc + 2] = v.z; tile[r * 65 + tc + 3] = v.w;
  }
  __syncthreads();
#pragma unroll
  for (int rr = 0; rr < 4; ++rr) {
    int r = rr * 16 + tr;
    int n = n0 + r;
    int kBase = k0 + tc;
    f16x4 o;
#pragma unroll
    for (int c = 0; c < 4; ++c) o[c] = (f16)tile[(tc + c) * 65 + r];
    int nt = n >> 7, nn = n & 127;
    int kt = kBase >> 5, kc = (kBase >> 3) & 3, j = kBase & 7;
    *(f16x4*)(Wb + ((size_t)nt * KT + kt) * 4096 + (kc * 128 + nn) * 8 + j) = o;
  }
}

__global__ __launch_bounds__(256) void prep_kernel(const float* __restrict__ X,
                                                   f16* __restrict__ Xb,
                                                   const float* __restrict__ Wqkv,
                                                   f16* __restrict__ Wqkvb,
                                                   const float* __restrict__ Wout,
                                                   f16* __restrict__ Woutb) {
  __shared__ float tile[64 * 65];
  int bz = blockIdx.x;
  if (bz < 2048) {
    int kt = bz & 63, rt = bz >> 6;
    int t = threadIdx.x;
    int m = t >> 1, half = t & 1;
    const float* src = X + (size_t)(rt * 128 + m) * HDIM + kt * 32 + half * 16;
    float4 v0 = ((const float4*)src)[0];
    float4 v1 = ((const float4*)src)[1];
    float4 v2 = ((const float4*)src)[2];
    float4 v3 = ((const float4*)src)[3];
    f16x8 a = {(f16)v0.x, (f16)v0.y, (f16)v0.z, (f16)v0.w,
               (f16)v1.x, (f16)v1.y, (f16)v1.z, (f16)v1.w};
    f16x8 b = {(f16)v2.x, (f16)v2.y, (f16)v2.z, (f16)v2.w,
               (f16)v3.x, (f16)v3.y, (f16)v3.z, (f16)v3.w};
    f16* dst = Xb + ((size_t)rt * 64 + kt) * 4096 + ((half * 2) * 128 + m) * 8;
    *(f16x8*)dst = a;
    *(f16x8*)(dst + 1024) = b;
  } else if (bz < 5120) {
    int u = bz - 2048;                 // 96 n-blocks x 32 k-blocks
    int nx = u % 96, ky = u / 96;
    transpose_tile(Wqkv, Wqkvb, HDIM, QKVN, ky * 64, nx * 64, tile);
  } else {
    int u = bz - 5120;                 // 32 x 32
    int nx = u & 31, ky = u >> 5;
    transpose_tile(Wout, Woutb, HDIM, HDIM, ky * 64, nx * 64, tile);
  }
}

// ---------------- GEMM: C = A * B^T (+bias), blocked operands ----------------
// MODE 1: QKV split -> Qr row-major f16, KB/VB attention-blocked (bias added).
//         moff: m-tile offset (gemm1 runs as two M-half dispatches).
// MODE 2: f16 partial to Cpart[z], K split by blockIdx.z (no bias).
template <int MODE>
__global__ __launch_bounds__(256) void gemm_kernel(const f16* __restrict__ Ablk,
                                                   const f16* __restrict__ Bblk,
                                                   const float* __restrict__ bias,
                                                   f16* __restrict__ Cpart,
                                                   f16* __restrict__ Qr,
                                                   f16* __restrict__ KB,
                                                   f16* __restrict__ VB,
                                                   int moff, int M, int N, int K) {
  __shared__ f16 As[4 * 128 * 8];
  __shared__ f16 Bs[4 * 128 * 8];
  int tid = threadIdx.x;
  int lane = tid & 63, w = tid >> 6;
  int lhi = lane >> 4, llo = lane & 15;
  int by = moff + blockIdx.y;
  int m0 = by * 128, n0 = blockIdx.x * 128;
  int wm = (w & 1) * 64, wn = (w >> 1) * 64;
  int KT = K >> 5;
  const f16* Ab = Ablk + (size_t)by * KT * 4096;
  const f16* Bb = Bblk + (size_t)blockIdx.x * KT * 4096;

  int ktBeg = 0, ktEnd = KT;
  if (MODE == 2) { int half = KT >> 1; ktBeg = blockIdx.z * half; ktEnd = ktBeg + half; }

  f32x4 acc[4][4];
#pragma unroll
  for (int i = 0; i < 4; ++i)
#pragma unroll
    for (int j = 0; j < 4; ++j) acc[i][j] = (f32x4){0.f, 0.f, 0.f, 0.f};

  for (int kt = ktBeg; kt < ktEnd; ++kt) {
    __syncthreads();
#pragma unroll
    for (int i2 = 0; i2 < 2; ++i2) {
      int Lw = i2 * 256 + w * 64;
      gl_lds16(Ab + (size_t)kt * 4096 + Lw * 8 + (lane * 8), As + Lw * 8);
      gl_lds16(Bb + (size_t)kt * 4096 + Lw * 8 + (lane * 8), Bs + Lw * 8);
    }
    __syncthreads();

    f16x8 af[4], bf[4];
#pragma unroll
    for (int i = 0; i < 4; ++i)
      af[i] = *(const f16x8*)(As + (lhi * 128 + wm + i * 16 + llo) * 8);
#pragma unroll
    for (int j = 0; j < 4; ++j)
      bf[j] = *(const f16x8*)(Bs + (lhi * 128 + wn + j * 16 + llo) * 8);
#pragma unroll
    for (int i = 0; i < 4; ++i)
#pragma unroll
      for (int j = 0; j < 4; ++j) acc[i][j] = MFMA16(af[i], bf[j], acc[i][j]);
  }

#pragma unroll
  for (int j = 0; j < 4; ++j) {
    int col = n0 + wn + j * 16 + llo;
    float bv = (MODE == 1) ? bias[col] : 0.f;
#pragma unroll
    for (int i = 0; i < 4; ++i) {
      int rowb = m0 + wm + i * 16 + lhi * 4;
      if (MODE == 2) {
        size_t zoff = (size_t)blockIdx.z * M * N;
#pragma unroll
        for (int r = 0; r < 4; ++r)
          Cpart[zoff + (size_t)(rowb + r) * N + col] = (f16)acc[i][j][r];
      } else {
        int region = n0 >> 11;  // 0:Q 1:K 2:V
        if (region == 0) {
#pragma unroll
          for (int r = 0; r < 4; ++r)
            Qr[(size_t)(rowb + r) * HDIM + col] = (f16)(acc[i][j][r] + bv);
        } else if (region == 1) {
          int cK = col - HDIM;
          int hd = cK >> 7, d = cK & 127, g = d >> 3, dj = d & 7;
#pragma unroll
          for (int r = 0; r < 4; ++r) {
            int row = rowb + r;
            int b = row >> 11, s = row & 2047;
            int kt2 = s >> 6, key = s & 63;
            size_t addr = ((((size_t)(b * 16 + hd) * 32 + kt2) * 16 + g) * 64 + key) * 8 + dj;
            KB[addr] = (f16)(acc[i][j][r] + bv);
          }
        } else {
          int cV = col - 2 * HDIM;
          int hd = cV >> 7, d = cV & 127;
          int row = rowb;
          int b = row >> 11, s = row & 2047;
          int kt2 = s >> 6, key = s & 63;
          int kg = key >> 3, kj = key & 7;
          f16x4 pv = {(f16)(acc[i][j][0] + bv), (f16)(acc[i][j][1] + bv),
                      (f16)(acc[i][j][2] + bv), (f16)(acc[i][j][3] + bv)};
          size_t addr = ((((size_t)(b * 16 + hd) * 32 + kt2) * 8 + kg) * 128 + d) * 8 + kj;
          *(f16x4*)(VB + addr) = pv;
        }
      }
    }
  }
}

// ---------------- bias + split-K merge -> f32 out ----------------
__global__ __launch_bounds__(256) void merge_out_kernel(const f16* __restrict__ Cpart,
                                                        const float* __restrict__ bias,
                                                        float* __restrict__ out) {
  int t = blockIdx.x * 256 + threadIdx.x;   // MROWS*HDIM/8 threads
  int col8 = (t & 255) * 8;
  int row = t >> 8;
  size_t base = (size_t)row * HDIM + col8;
  const size_t MN = (size_t)MROWS * HDIM;
  f16x8 a = *(const f16x8*)(Cpart + base);
  f16x8 b = *(const f16x8*)(Cpart + MN + base);
  float4 b0 = *(const float4*)(bias + col8);
  float4 b1 = *(const float4*)(bias + col8 + 4);
  float4 o0 = {(float)a[0] + (float)b[0] + b0.x, (float)a[1] + (float)b[1] + b0.y,
               (float)a[2] + (float)b[2] + b0.z, (float)a[3] + (float)b[3] + b0.w};
  float4 o1 = {(float)a[4] + (float)b[4] + b1.x, (float)a[5] + (float)b[5] + b1.y,
               (float)a[6] + (float)b[6] + b1.z, (float)a[7] + (float)b[7] + b1.w};
  *(float4*)(out + base) = o0;
  *(float4*)(out + base + 4) = o1;
}

// ---------------- causal flash attention (round-5 form, best measured) --------
// Block: 256 thr = 4 waves; q-tile = 128 rows (32/wave); key-tiles of 64.
// grid.x = 24: gx<8 -> qt=gx single block; gx>=8 -> qt=8+(gx-8)/2, 2 key-splits.
// S^T = K Q^T (32x32x16), fixed-max softmax p = exp2(s*C1 - C2), O^T = V^T P^T.
__global__ __launch_bounds__(256, 3) void attn_kernel(const f16* __restrict__ Qr,
                                                      const f16* __restrict__ KB,
                                                      const f16* __restrict__ VB,
                                                      f16* __restrict__ Opart,
                                                      float* __restrict__ Lpart) {
  __shared__ f16 Ks[1024 * 8];     // [g(16)][key(64)][8]
  __shared__ f16 Vs[1024 * 8];     // [kg(8)][d(128)][8]
  __shared__ f16 Ps[4][32 * 72];   // per-wave [q(32)][key(64)] stride 72

  int tid = threadIdx.x, lane = tid & 63, w = tid >> 6;
  int l5 = lane & 31, hl = lane >> 5;
  int bh = blockIdx.y, b = bh >> 4, hd = bh & 15;
  int gx = blockIdx.x;
  int qt, kt0, kt1, slot;
  if (gx < 8) { qt = gx; slot = 0; kt0 = 0; kt1 = 2 * qt + 2; }
  else {
    qt = 8 + ((gx - 8) >> 1); slot = (gx - 8) & 1;
    kt0 = slot ? (qt + 1) : 0;
    kt1 = slot ? (2 * qt + 2) : (qt + 1);
  }

  int qbase = qt * 128 + w * 32;
  int qrow = qbase + l5;

  const f16* qp = Qr + (size_t)(b * S_LEN + qrow) * HDIM + hd * DHEAD + hl * 8;
  f16x8 qf[8];
#pragma unroll
  for (int s8 = 0; s8 < 8; ++s8) qf[s8] = *(const f16x8*)(qp + s8 * 16);

  f32x16 oac[4];
#pragma unroll
  for (int mt = 0; mt < 4; ++mt)
#pragma unroll
    for (int r = 0; r < 16; ++r) oac[mt][r] = 0.f;
  float rs = 0.f;

  const float C1 = 0.12752747419986393f;   // log2(e)/sqrt(128)
  const float C2 = 11.541560327111708f;    // 8 * log2(e)

  const f16* KBb = KB + (size_t)bh * 32 * 8192;
  const f16* VBb = VB + (size_t)bh * 32 * 8192;

  for (int kt = kt0; kt < kt1; ++kt) {
    __syncthreads();
    {
      const f16* Kt = KBb + (size_t)kt * 8192;
      const f16* Vt = VBb + (size_t)kt * 8192;
#pragma unroll
      for (int c = 0; c < 4; ++c) {
        int u0 = w * 256 + c * 64;
        gl_lds16(Kt + (size_t)(u0 + lane) * 8, Ks + u0 * 8);
        gl_lds16(Vt + (size_t)(u0 + lane) * 8, Vs + u0 * 8);
      }
    }
    __syncthreads();

    if (kt * 64 <= qbase + 31) {
      f32x16 sac[2];
#pragma unroll
      for (int mt = 0; mt < 2; ++mt)
#pragma unroll
        for (int r = 0; r < 16; ++r) sac[mt][r] = 0.f;
#pragma unroll
      for (int s8 = 0; s8 < 8; ++s8) {
#pragma unroll
        for (int mt = 0; mt < 2; ++mt) {
          f16x8 kf = *(const f16x8*)(Ks + ((s8 * 2 + hl) * 64 + mt * 32 + l5) * 8);
          sac[mt] = MFMA32(kf, qf[s8], sac[mt]);
        }
      }

      bool diag = (kt * 64 + 63 > qbase);
#pragma unroll
      for (int mt = 0; mt < 2; ++mt) {
#pragma unroll
        for (int g4 = 0; g4 < 4; ++g4) {
          f16x4 pk;
#pragma unroll
          for (int r = 0; r < 4; ++r) {
            int keyl = mt * 32 + g4 * 8 + hl * 4 + r;
            float p = __builtin_amdgcn_exp2f(fmaf(sac[mt][g4 * 4 + r], C1, -C2));
            if (diag && (kt * 64 + keyl > qrow)) p = 0.f;
            rs += p;
            pk[r] = (f16)p;
          }
          *(f16x4*)(&Ps[w][l5 * 72 + mt * 32 + g4 * 8 + hl * 4]) = pk;
        }
      }
      asm volatile("s_waitcnt lgkmcnt(0)" ::: "memory");  // same-wave P write->read

#pragma unroll
      for (int ks = 0; ks < 4; ++ks) {
        f16x8 pf = *(const f16x8*)(&Ps[w][l5 * 72 + ks * 16 + hl * 8]);
#pragma unroll
        for (int mt = 0; mt < 4; ++mt) {
          f16x8 vf = *(const f16x8*)(Vs + ((ks * 2 + hl) * 128 + mt * 32 + l5) * 8);
          oac[mt] = MFMA32(vf, pf, oac[mt]);
        }
      }
    }
  }

  float lsum = rs + __shfl_xor(rs, 32, 64);
  size_t ob = ((size_t)slot * 32 + bh) * S_LEN * DHEAD + (size_t)qrow * DHEAD;
#pragma unroll
  for (int mt = 0; mt < 4; ++mt) {
#pragma unroll
    for (int g4 = 0; g4 < 4; ++g4) {
      int d = mt * 32 + g4 * 8 + hl * 4;
      f16x4 ov = {(f16)oac[mt][g4 * 4 + 0], (f16)oac[mt][g4 * 4 + 1],
                  (f16)oac[mt][g4 * 4 + 2], (f16)oac[mt][g4 * 4 + 3]};
      *(f16x4*)(Opart + ob + d) = ov;
    }
  }
  if (hl == 0) Lpart[((size_t)slot * 32 + bh) * S_LEN + qrow] = lsum;
}

// ---------------- merge attn partials -> CTX blocked f16 ----------------
__global__ __launch_bounds__(256) void merge_kernel(const f16* __restrict__ Opart,
                                                    const float* __restrict__ Lpart,
                                                    f16* __restrict__ CTXb) {
  int t = blockIdx.x * 256 + threadIdx.x;  // 32*2048*16 threads
  int d8 = (t & 15) * 8;
  int q = (t >> 4) & 2047;
  int bh = t >> 15;
  int b = bh >> 4, hd = bh & 15;
  int ns = ((q >> 7) >= 8) ? 2 : 1;
  size_t o0 = ((size_t)bh * S_LEN + q) * DHEAD + d8;
  const size_t OSLOT = (size_t)32 * S_LEN * DHEAD;
  float l = Lpart[(size_t)bh * S_LEN + q];
  f16x8 a = *(const f16x8*)(Opart + o0);
  float acc[8];
#pragma unroll
  for (int j = 0; j < 8; ++j) acc[j] = (float)a[j];
  if (ns == 2) {
    l += Lpart[OSLOT / DHEAD + (size_t)bh * S_LEN + q];
    f16x8 a2 = *(const f16x8*)(Opart + OSLOT + o0);
#pragma unroll
    for (int j = 0; j < 8; ++j) acc[j] += (float)a2[j];
  }
  float inv = 1.0f / l;
  f16x8 o;
#pragma unroll
  for (int j = 0; j < 8; ++j) o[j] = (f16)(acc[j] * inv);
  // blocked write: row = b*S+q, col = hd*128+d8  (K = HDIM, KT = 64)
  int row = b * S_LEN + q;
  int col = hd * DHEAD + d8;
  int rt = row >> 7, rr = row & 127;
  int kt = col >> 5, kc = (col >> 3) & 3;
  *(f16x8*)(CTXb + ((size_t)rt * 64 + kt) * 4096 + (kc * 128 + rr) * 8) = o;
}

// ---------------- launch ----------------
extern "C" void kernel_launch(void* const* d_in, const int* in_sizes, int n_in,
                              void* d_out, int out_size, void* d_ws, size_t ws_size,
                              hipStream_t stream) {
  const float* X    = (const float*)d_in[0];
  const float* Wqkv = (const float*)d_in[2];
  const float* bqkv = (const float*)d_in[3];
  const float* Wout = (const float*)d_in[4];
  const float* bout = (const float*)d_in[5];
  float* out = (float*)d_out;

  char* ws = (char*)d_ws;
  f16* Xb    = (f16*)ws;  ws += (size_t)MROWS * HDIM * sizeof(f16);    // 16 MiB (reused as CTXb)
  f16* Wqkvb = (f16*)ws;  ws += (size_t)QKVN * HDIM * sizeof(f16);     // 24 MiB
  f16* Woutb = (f16*)ws;  ws += (size_t)HDIM * HDIM * sizeof(f16);     // 8 MiB
  f16* Qr    = (f16*)ws;  ws += (size_t)MROWS * HDIM * sizeof(f16);    // 16 MiB
  f16* KB    = (f16*)ws;  ws += (size_t)32 * 32 * 8192 * sizeof(f16);  // 16 MiB
  f16* VB    = (f16*)ws;  ws += (size_t)32 * 32 * 8192 * sizeof(f16);  // 16 MiB
  f16* Opart = (f16*)ws;  ws += (size_t)2 * 32 * S_LEN * DHEAD * sizeof(f16);  // 32 MiB
  float* Lpart = (float*)ws;  ws += (size_t)2 * 32 * S_LEN * sizeof(float);    // 512 KiB
  f16* CTXb  = Xb;        // Xb dead after QKV GEMM
  f16* Cpart = Opart;     // Opart dead after merge_kernel; 2*M*N*2B = 32 MiB fits

  prep_kernel<<<6144, 256, 0, stream>>>(X, Xb, Wqkv, Wqkvb, Wout, Woutb);

  // QKV GEMM as two M-half dispatches (768 blocks each = 3/CU) so the slowest
  // single dispatch drops to ~70us and attn can surface in the profile.
  gemm_kernel<1><<<dim3(QKVN / 128, 16), 256, 0, stream>>>(
      Xb, Wqkvb, bqkv, nullptr, Qr, KB, VB, 0, MROWS, QKVN, HDIM);
  gemm_kernel<1><<<dim3(QKVN / 128, 16), 256, 0, stream>>>(
      Xb, Wqkvb, bqkv, nullptr, Qr, KB, VB, 16, MROWS, QKVN, HDIM);

  attn_kernel<<<dim3(24, 32), 256, 0, stream>>>(Qr, KB, VB, Opart, Lpart);

  merge_kernel<<<(32 * S_LEN * 16) / 256, 256, 0, stream>>>(Opart, Lpart, CTXb);

  gemm_kernel<2><<<dim3(HDIM / 128, 32, 2), 256, 0, stream>>>(
      CTXb, Woutb, nullptr, Cpart, nullptr, nullptr, nullptr, 0, MROWS, HDIM, HDIM);

  merge_out_kernel<<<(MROWS * HDIM / 8) / 256, 256, 0, stream>>>(Cpart, bout, out);
}